// Round 14
// baseline (239.511 us; speedup 1.0000x reference)
//
#include <hip/hip_runtime.h>
#include <hip/hip_bf16.h>
#include <math.h>

#define N_Q 16384
#define N_M 16384
#define DIM 128
#define KNN 5
#define SPLITS 8
#define COLS_PER_SPLIT (N_M / SPLITS)   // 2048
#define TILE_COLS 256
#define ITERS (COLS_PER_SPLIT / TILE_COLS)  // 8
#define BROWS 256                        // rows per block (4 waves x 64)
#define TSEL 8                           // keys kept per (row, split)
#define TSEL2 16                         // candidates re-ranked per query
#define LLIST 4                          // per-lane sorted list depth
#define BIGF 3.0e38f

typedef __bf16 bf16x8 __attribute__((ext_vector_type(8)));
typedef float f32x4 __attribute__((ext_vector_type(4)));

__device__ __forceinline__ void gl2lds16(const void* g, void* l) {
    __builtin_amdgcn_global_load_lds(
        (const __attribute__((address_space(1))) void*)g,
        (__attribute__((address_space(3))) void*)l, 16, 0, 0);
}

// med3: with a<=b (sorted list invariant), med3(a,b,k) == max(a, min(b,k)).
__device__ __forceinline__ unsigned umed3(unsigned a, unsigned b, unsigned c) {
    unsigned d;
    asm("v_med3_u32 %0, %1, %2, %3" : "=v"(d) : "v"(a), "v"(b), "v"(c));
    return d;
}

// branchless sorted insert (ascending), depth D: (D-1) med3 + 1 min.
template <int D>
__device__ __forceinline__ void insD(unsigned (&L)[D], unsigned k) {
#pragma unroll
    for (int i = D - 1; i >= 1; --i) L[i] = umed3(L[i - 1], L[i], k);
    L[0] = min(L[0], k);
}

// ---------------------------------------------------------------------------
// Kernel A: prep. Query waves: bf16 convert only (qb). Mem waves: mb = -2x
// row in bf16 (B operand carries the -2) + sumsq -> m2b = m2 + 256 (bias so
// key s = m2b - 2*dot > 0: uint order == score order).
// ---------------------------------------------------------------------------
__global__ void prep_kernel(const float* __restrict__ q,
                            const float* __restrict__ mem,
                            float* __restrict__ m2b,
                            __hip_bfloat16* __restrict__ qb,
                            __hip_bfloat16* __restrict__ mb) {
    int gt = blockIdx.x * blockDim.x + threadIdx.x;
    int wid = gt >> 6;
    int lane = gt & 63;
    bool isq = wid < N_Q;
    int r = isq ? wid : wid - N_Q;
    const float* src = (isq ? q : mem) + (size_t)r * DIM;
    __hip_bfloat16* bdst = (isq ? qb : mb) + (size_t)r * DIM;
    float2 v = reinterpret_cast<const float2*>(src)[lane];
    float sc = isq ? 1.0f : -2.0f;
    __hip_bfloat162 bv;
    bv.x = __float2bfloat16(sc * v.x);
    bv.y = __float2bfloat16(sc * v.y);
    reinterpret_cast<__hip_bfloat162*>(bdst)[lane] = bv;
    if (!isq) {
        float s = fmaf(v.x, v.x, v.y * v.y);
#pragma unroll
        for (int off = 32; off > 0; off >>= 1) s += __shfl_down(s, off, 64);
        if (lane == 0) m2b[r] = s + 256.0f;
    }
}

// ---------------------------------------------------------------------------
// Kernel B: bf16 MFMA scoring + branchless med3 top-4 selection.
// r12 structure (BROWS=256, 4 row-tiles/wave: each ds_read_b128 B-frag
// feeds 4 MFMAs) with a 256-col tile (64 KB LDS, ITERS=8): HALF the
// barrier+vmcnt-drain events of r12 — the residency is pinned at
// 2 blocks/CU regardless (r11/r13 falsified the occupancy knobs), so the
// barrier drain is the remaining per-tile tax worth amortizing.
// acc C-init = m2b; key = and_or(pack) + 4-op insert.
// ---------------------------------------------------------------------------
__global__ __launch_bounds__(256, 2) void knn_tops_kernel(
    const __hip_bfloat16* __restrict__ qb, const __hip_bfloat16* __restrict__ mb,
    const float* __restrict__ m2b, unsigned* __restrict__ candK) {
    __shared__ __align__(16) unsigned char smem[65536];  // 64KB tile / merge ovl
    const int tid = threadIdx.x;
    const int w = tid >> 6;
    const int lane = tid & 63;
    const int i16 = lane & 15;
    const int g = lane >> 4;
    const int row0 = blockIdx.x * BROWS;
    const int col0 = blockIdx.y * COLS_PER_SPLIT;

    // ---- A fragments: 4 row-tiles x 4 k-steps (loop-invariant) ----
    bf16x8 afrag[4][4];
#pragma unroll
    for (int ti = 0; ti < 4; ++ti) {
        const __hip_bfloat16* qrow =
            qb + (size_t)(row0 + w * 64 + ti * 16 + i16) * DIM;
#pragma unroll
        for (int ks = 0; ks < 4; ++ks)
            afrag[ti][ks] = *reinterpret_cast<const bf16x8*>(qrow + ks * 32 + g * 8);
    }

    // ---- sorted lists (packed keys), 16 rows x 4, ascending ----
    unsigned lst[16][LLIST];
#pragma unroll
    for (int rr = 0; rr < 16; ++rr)
#pragma unroll
        for (int j = 0; j < LLIST; ++j) lst[rr][j] = 0xFFFFFFFFu;

    // ---- loop-invariant addressing ----
    const int lds_base = i16 * 256 + ((g ^ (i16 & 7)) << 4);
    int soff[16];
#pragma unroll
    for (int it = 0; it < 16; ++it) {
        int fg = w * 1024 + it * 64 + lane;   // granule slot (16 per col)
        int c = fg >> 4, sg = fg & 15;
        int gk = (sg & 8) | ((sg ^ c) & 7);
        soff[it] = c * DIM + gk * 8;
    }
    const __hip_bfloat16* mbt = mb + (size_t)col0 * DIM;

    for (int t = 0; t < ITERS; ++t) {
        __syncthreads();  // all waves done reading previous tile
#pragma unroll
        for (int it = 0; it < 16; ++it)
            gl2lds16(mbt + soff[it], smem + w * 16384 + it * 1024);
        mbt += TILE_COLS * DIM;
        __syncthreads();

        // per-tile m2b (16 col-tiles' worth for this lane)
        float m2r[16];
#pragma unroll
        for (int c = 0; c < 16; ++c)
            m2r[c] = m2b[col0 + t * TILE_COLS + c * 16 + i16];
        const unsigned colb = (unsigned)(col0 + t * TILE_COLS + i16);

#pragma unroll
        for (int cc = 0; cc < 8; ++cc) {  // ct chunk of 2
            f32x4 acc[4][2];
#pragma unroll
            for (int ti = 0; ti < 4; ++ti)
#pragma unroll
                for (int c2 = 0; c2 < 2; ++c2) {
                    float m = m2r[cc * 2 + c2];
                    acc[ti][c2] = (f32x4){m, m, m, m};
                }
#pragma unroll
            for (int ks = 0; ks < 4; ++ks) {
                const unsigned char* bp = smem + (lds_base ^ (ks << 6));
#pragma unroll
                for (int c2 = 0; c2 < 2; ++c2) {
                    int ct = cc * 2 + c2;
                    bf16x8 bfr =
                        *reinterpret_cast<const bf16x8*>(bp + ct * 4096);
#pragma unroll
                    for (int ti = 0; ti < 4; ++ti)
                        acc[ti][c2] = __builtin_amdgcn_mfma_f32_16x16x32_bf16(
                            afrag[ti][ks], bfr, acc[ti][c2], 0, 0, 0);
                }
            }
#pragma unroll
            for (int ti = 0; ti < 4; ++ti) {
#pragma unroll
                for (int r = 0; r < 4; ++r) {
                    const int rr = ti * 4 + r;
#pragma unroll
                    for (int c2 = 0; c2 < 2; ++c2) {
                        unsigned k = (__float_as_uint(acc[ti][c2][r]) &
                                      0xFFFFC000u) |
                                     (colb + (cc * 2 + c2) * 16);
                        insD(lst[rr], k);
                    }
                }
            }
        }
    }

    __syncthreads();  // tile LDS dead; overlay merge buffer

    // ---- phase 1: SNAPSHOT partner's 4 keys, then insert ----
#pragma unroll
    for (int rr = 0; rr < 16; ++rr) {
        unsigned pv[LLIST];
#pragma unroll
        for (int j = 0; j < LLIST; ++j)
            pv[j] = (unsigned)__shfl_xor((int)lst[rr][j], 8, 64);
#pragma unroll
        for (int j = 0; j < LLIST; ++j) insD(lst[rr], pv[j]);
    }
    // ---- dump: 8 lanes x 4 keys per row, stride 33 ([256][33] = 33.8 KB) ----
    unsigned* MG = (unsigned*)smem;
    if (i16 < 8) {
#pragma unroll
        for (int rr = 0; rr < 16; ++rr) {
            int row = w * 64 + (rr >> 2) * 16 + g * 4 + (rr & 3);
#pragma unroll
            for (int j = 0; j < LLIST; ++j)
                MG[row * 33 + i16 * LLIST + j] = lst[rr][j];
        }
    }
    __syncthreads();
    // ---- phase 2: all 256 threads, one per row; med3 depth-8 over 32 keys ----
    {
        unsigned bk[TSEL];
#pragma unroll
        for (int j = 0; j < TSEL; ++j) bk[j] = 0xFFFFFFFFu;
        for (int c = 0; c < 32; ++c) {
            unsigned k = MG[tid * 33 + c];
            insD(bk, k);
        }
        size_t base = (size_t)(row0 + tid) * (SPLITS * TSEL) + blockIdx.y * TSEL;
        *reinterpret_cast<uint4*>(candK + base) =
            make_uint4(bk[0], bk[1], bk[2], bk[3]);
        *reinterpret_cast<uint4*>(candK + base + 4) =
            make_uint4(bk[4], bk[5], bk[6], bk[7]);
    }
}

// ---------------------------------------------------------------------------
// Kernel C: FUSED merge + exact fp32 re-rank + adaptive-KNN output.
// Block = 256 threads, 64 queries. Phase 1 (replay-proven merge logic):
// thread per query scans its 64 packed keys -> top-16 indices -> LDS.
// Barrier. Phase 2 (replay-proven finalize body): wave per query, 16
// queries per wave sequentially; quad-cooperative sum-sq-diff distances;
// 5 shuffle-argmin extractions -> exact top-5 -> output.
// ---------------------------------------------------------------------------
__global__ __launch_bounds__(256) void finalize_kernel(
    const float* __restrict__ q, const float* __restrict__ mem,
    const unsigned* __restrict__ candK, const float* __restrict__ scaleb,
    float* __restrict__ out) {
    __shared__ int candS[64 * TSEL2];
    const int tid = threadIdx.x;
    const int n0 = blockIdx.x * 64;

    if (tid < 64) {
        const unsigned* ck = candK + (size_t)(n0 + tid) * (SPLITS * TSEL);
        unsigned v[TSEL2];
#pragma unroll
        for (int j = 0; j < TSEL2; ++j) v[j] = 0xFFFFFFFFu;
        for (int s4 = 0; s4 < (SPLITS * TSEL) / 4; ++s4) {
            uint4 kk = reinterpret_cast<const uint4*>(ck)[s4];
            insD(v, kk.x);
            insD(v, kk.y);
            insD(v, kk.z);
            insD(v, kk.w);
        }
#pragma unroll
        for (int j = 0; j < TSEL2; ++j)
            candS[tid * TSEL2 + j] = (int)(v[j] & 0x3FFFu);
    }
    __syncthreads();

    const int wv = tid >> 6, lane = tid & 63;
    const int cand = lane >> 2, qd = lane & 3;
    for (int i = 0; i < 16; ++i) {
        const int qi = wv * 16 + i;
        const int n = n0 + qi;
        int ci = candS[qi * TSEL2 + cand];
        const float4* qr =
            reinterpret_cast<const float4*>(q + (size_t)n * DIM) + qd * 8;
        const float4* mr =
            reinterpret_cast<const float4*>(mem + (size_t)ci * DIM) + qd * 8;
        float d2 = 0.f;
#pragma unroll
        for (int k = 0; k < 8; ++k) {
            float4 a = qr[k], b = mr[k];
            float dx = a.x - b.x, dy = a.y - b.y;
            float dz = a.z - b.z, dw = a.w - b.w;
            d2 = fmaf(dx, dx, d2);
            d2 = fmaf(dy, dy, d2);
            d2 = fmaf(dz, dz, d2);
            d2 = fmaf(dw, dw, d2);
        }
        d2 += __shfl_xor(d2, 1, 64);
        d2 += __shfl_xor(d2, 2, 64);
        float v = (qd == 0) ? d2 : BIGF;

        float dk[KNN]; int ik[KNN];
#pragma unroll
        for (int r = 0; r < KNN; ++r) {
            float mv = v; int ml = lane;
#pragma unroll
            for (int off = 32; off > 0; off >>= 1) {
                float ov = __shfl_xor(mv, off, 64);
                int   ol = __shfl_xor(ml, off, 64);
                if (ov < mv || (ov == mv && ol < ml)) { mv = ov; ml = ol; }
            }
            dk[r] = sqrtf(fmaxf(mv, 1e-12f));
            ik[r] = __shfl(ci, ml, 64);
            if (lane == ml) v = BIGF;
        }
        if (lane == 0) {
            float dmin = dk[0];
            float se = 0.f, wd = 0.f, sm = 0.f, ssc = 0.f;
#pragma unroll
            for (int j = 0; j < KNN; ++j) {
                float e = expf(-(dk[j] - dmin));
                se += e;
                wd = fmaf(e, dk[j], wd);
                sm += dk[j];
                ssc += scaleb[ik[j]];
            }
            wd /= se;
            float scale = ssc * 0.2f;
            float nd = wd / fmaxf(scale, 1e-6f);
            float mean = sm * 0.2f;
            float var = 0.f;
#pragma unroll
            for (int j = 0; j < KNN; ++j) {
                float dd = dk[j] - mean;
                var = fmaf(dd, dd, var);
            }
            var *= 0.2f;
            float cons = sqrtf(var) / fmaxf(mean, 1e-6f);
            out[n] = nd * (1.f + 0.5f * cons);
        }
    }
}

// ---------------------------------------------------------------------------
// ws: m2b[M] f32 | qb bf16 | mb bf16(-2x) | candK[N*64] u32  (~12.3 MB)
// ---------------------------------------------------------------------------
extern "C" void kernel_launch(void* const* d_in, const int* in_sizes, int n_in,
                              void* d_out, int out_size, void* d_ws,
                              size_t ws_size, hipStream_t stream) {
    const float* query  = (const float*)d_in[0];
    const float* mem    = (const float*)d_in[1];
    const float* scaleb = (const float*)d_in[2];
    float* out = (float*)d_out;

    float* m2b = (float*)d_ws;
    __hip_bfloat16* qb = (__hip_bfloat16*)(m2b + N_M);
    __hip_bfloat16* mb = qb + (size_t)N_Q * DIM;
    unsigned* candK = (unsigned*)(mb + (size_t)N_M * DIM);

    prep_kernel<<<(N_Q + N_M) / 4, 256, 0, stream>>>(query, mem, m2b, qb, mb);
    dim3 gridB(N_Q / BROWS, SPLITS);
    knn_tops_kernel<<<gridB, 256, 0, stream>>>(qb, mb, m2b, candK);
    finalize_kernel<<<N_Q / 64, 256, 0, stream>>>(query, mem, candK, scaleb,
                                                  out);
}